// Round 11
// baseline (97.988 us; speedup 1.0000x reference)
//
#include <hip/hip_runtime.h>
#include <hip/hip_fp16.h>

#define NBG   60
#define LMAX  30
#define MWC   59
#define CTR   29
#define NPAIR 20
#define NT    11          // |n| <= 5 truncation (validated r4-r10)
#define NTP   12
#define NOFF  5
#define PI_F  3.14159265358979323846f

// ---------------------------------------------------------------------------
// f32 Wigner small-d column scale*d^l_{mp,mn}(beta), Jacobi recurrence.
// Convention == expm(-(beta/2)(J+ - J-)), verified on-hardware r1-r10.
// ---------------------------------------------------------------------------
__device__ void wigner_colf(float beta, int mp, int mn, float scale,
                            float* out, int stride) {
  int a = mp - mn; if (a < 0) a = -a;
  int b = mp + mn; if (b < 0) b = -b;
  int lmin = (a + b) >> 1;
  for (int l = 0; l < LMAX; ++l) out[l * stride] = 0.0f;
  if (lmin >= LMAX) return;
  float sh, ch; sincosf(0.5f * beta, &sh, &ch);
  float x = ch * ch - sh * sh;
  float base = scale;
  for (int q = 0; q < a; ++q) base *= sh;
  for (int q = 0; q < b; ++q) base *= ch;
  if (mp >= mn && ((mp - mn) & 1)) base = -base;
  float K2 = 1.f;
  for (int q = 1; q <= a; ++q) K2 *= (float)(b + q) / (float)q;
  float Pm2 = 0.f, Pm1 = 1.f;
  out[lmin * stride] = base * sqrtf(K2);
  for (int s = 1; lmin + s < LMAX; ++s) {
    float Ps;
    if (s == 1) {
      Ps = (a + 1) + (a + b + 2) * 0.5f * (x - 1.f);
    } else {
      float t0 = 2.f * s + a + b;
      float c1 = 2.f * s * (s + a + b) * (t0 - 2.f);
      float c2 = (t0 - 1.f) * (t0 * (t0 - 2.f) * x + (float)(a * a - b * b));
      float c3 = 2.f * (s + a - 1.f) * (s + b - 1.f) * t0;
      Ps = (c2 * Pm1 - c3 * Pm2) / c1;
    }
    K2 *= ((float)s * (s + a + b)) / (((float)s + a) * ((float)s + b));
    out[(lmin + s) * stride] = base * sqrtf(K2) * Ps;
    Pm2 = Pm1; Pm1 = Ps;
  }
}

__device__ __forceinline__ float quad_w(int j) {
  float s = 0.f;
  for (int k = 0; k < 30; ++k) {
    int r = ((2 * j + 1) * (2 * k + 1)) % 240;
    s += sinf(2.f * PI_F * r / 240.f) / (float)(2 * k + 1);
  }
  return (2.f / 30.f) * sinf(PI_F * (2 * j + 1) / 120.f) * s;
}

// ---------------------------------------------------------------------------
// K1 (780 blocks x 256): all input-only work.
//  u 0        : scwF1/scwF2[nn][pair]  (scwF2 x pi for the synth/fft bridge)
//  u 1..59    : M = u-1: D0T[M][l][j] = wq[j]*d^l_{M-29,0}(beta_j)
//  u 60..539  : sgd[j][M][l][nn] = d^l_{M-29,nn-5}(beta_j)*(2l+1)*dk[l][nn]
//               (480 blocks: j = s>>3, 4-M chunks c = s&7 -> better overlap)
//  u 540..779 : alpha-DFT of x1 -> xfT[M][j][rb]
// ---------------------------------------------------------------------------
__global__ __launch_bounds__(256)
void k1_prep(const float* __restrict__ x1,
             const float* __restrict__ wc, const float* __restrict__ wd,
             float2* __restrict__ scwF1, float2* __restrict__ scwF2,
             float* __restrict__ D0T, float* __restrict__ sgd,
             float2* __restrict__ xfT) {
  __shared__ __align__(16) char smem[8704];
  int u = blockIdx.x, t = threadIdx.x;
  if (u == 0) {
    float*  swq  = (float*)smem;
    float2* swqn = (float2*)(smem + 256);
    if (t < NBG) swq[t] = quad_w(t);
    __syncthreads();
    if (t < NT) {
      int n = t - NOFF;
      float re = 0.f, im = 0.f;
      for (int g = 0; g < NBG; ++g) {
        int k = ((n * g) % NBG + NBG) % NBG;
        float sn, cs; sincosf(2.f * PI_F * k / 60.f, &sn, &cs);
        re += swq[g] * cs; im += swq[g] * sn;
      }
      swqn[t] = make_float2(re, im);
    }
    __syncthreads();
    if (t < NT * NPAIR) {
      int nn = t / NPAIR, pair = t - nn * NPAIR, n = nn - NOFF;
      float re1 = 0, im1 = 0, re2 = 0, im2 = 0;
      for (int p = 0; p < 6; ++p) {
        int k = ((n * p) % 6 + 6) % 6;
        float sn, cs; sincosf(2.f * PI_F * k / 6.f, &sn, &cs);
        float a1 = wc[pair * 6 + p], a2 = wd[pair * 6 + p];
        re1 += a1 * cs; im1 += a1 * sn;
        re2 += a2 * cs; im2 += a2 * sn;
      }
      float2 w = swqn[nn];
      scwF1[t] = make_float2(w.x * re1 - w.y * im1, w.x * im1 + w.y * re1);
      scwF2[t] = make_float2(PI_F * (w.x * re2 - w.y * im2),
                             PI_F * (w.x * im2 + w.y * re2));
    }
  } else if (u < 60) {
    int M = u - 1;
    if (t < NBG) {
      float wqj = quad_w(t);
      wigner_colf(PI_F * (2 * t + 1) / 120.f, M - CTR, 0, wqj,
                  D0T + (size_t)M * LMAX * NBG + t, NBG);
    }
  } else if (u < 540) {
    float* buf  = (float*)smem;           // [4][30][12] 5760
    float* dkwL = (float*)(smem + 5760);  // [30][12] 1440
    int s = u - 60, j = s >> 3, c = s & 7;
    int M0 = c * 4, nM = (c < 7) ? 4 : 2;
    if (t < nM * NT) {
      int Mi = t / NT, nn = t - Mi * NT;
      wigner_colf(PI_F * (2 * j + 1) / 120.f, M0 + Mi - CTR, nn - NOFF, 1.f,
                  &buf[Mi * 360 + nn], NTP);
    } else if (t >= 128 && t < 128 + NT) {
      int nn = t - 128;
      wigner_colf(PI_F / 160.f, nn - NOFF, 0, 1.f, dkwL + nn, NTP);
      for (int l = 0; l < LMAX; ++l) dkwL[l * NTP + nn] *= (float)(2 * l + 1);
    }
    __syncthreads();
    size_t base = (size_t)(j * 30 + M0) * 360;
    for (int q = t; q < nM * 360; q += 256) {
      int r = q % 360, nn = r % NTP;
      sgd[base + q] = (nn < NT) ? buf[q] * dkwL[r] : 0.f;
    }
  } else {
    float*  xr  = (float*)smem;            // [8][60] 1920
    float*  twc = (float*)(smem + 1920);
    float*  tws = (float*)(smem + 2160);
    float2* xo  = (float2*)(smem + 2400);  // [59][9] 4248
    int s = u - 540, j = s >> 2, qh = s & 3;
    for (int q = t; q < 8 * NBG; q += 256) {
      int bl = q / NBG, a = q - bl * NBG;
      xr[bl * NBG + a] = x1[((size_t)(qh * 8 + bl) * NBG + j) * NBG + a];
    }
    if (t < NBG) {
      float sn, cs; sincosf(-2.f * PI_F * t / 60.f, &sn, &cs);
      twc[t] = cs; tws[t] = sn;
    }
    __syncthreads();
    for (int q = t; q < 8 * MWC; q += 256) {
      int bl = q / MWC, M = q - bl * MWC, mm = M - CTR;
      const float* xp = xr + bl * NBG;
      float re = 0.f, im = 0.f; int k = 0;
      for (int a = 0; a < NBG; ++a) {
        re += xp[a] * twc[k]; im += xp[a] * tws[k];
        k += mm; if (k >= NBG) k -= NBG; if (k < 0) k += NBG;
      }
      const float sc = 2.f * PI_F / 60.f;
      xo[M * 9 + bl] = make_float2(re * sc, im * sc);
    }
    __syncthreads();
    for (int q = t; q < MWC * 8; q += 256) {
      int M = q / 8, bl = q - M * 8;
      xfT[((size_t)M * NBG + j) * 32 + qh * 8 + bl] = xo[M * 9 + bl];
    }
  }
}

// ---------------------------------------------------------------------------
// K2 ana1 (472 = M*8 + lq*2 + wh, 128 thr): 8 l's x 16 b's, all lanes active.
// X21[M][l][wh*16+b] = sum_j D0T[M,l,j] * xfT[M,j,2b+wh]
// ---------------------------------------------------------------------------
__global__ __launch_bounds__(128)
void k_ana1(const float2* __restrict__ xfT, const float* __restrict__ D0T,
            float2* __restrict__ X21) {
  __shared__ float2 sxf[NBG][16];   // 7680
  __shared__ float  sD[8][NBG];     // 1920
  int bi = blockIdx.x;
  int M = bi >> 3, lq = (bi >> 1) & 3, wh = bi & 1;
  int t = threadIdx.x;
  for (int q = t; q < NBG * 16; q += 128) {
    int jj = q >> 4, b = q & 15;
    sxf[jj][b] = xfT[((size_t)M * NBG + jj) * 32 + b * 2 + wh];
  }
  for (int q = t; q < 8 * NBG; q += 128) {
    int ll = q / NBG, jj = q - ll * NBG, l = lq * 8 + ll;
    sD[ll][jj] = (l < LMAX) ? D0T[((size_t)M * LMAX + l) * NBG + jj] : 0.f;
  }
  __syncthreads();
  int ll = t >> 4, b = t & 15;
  int l = lq * 8 + ll;
  if (l < LMAX) {
    float re = 0.f, im = 0.f;
#pragma unroll 6
    for (int jj = 0; jj < NBG; ++jj) {
      float d = sD[ll][jj];
      float2 v = sxf[jj][b];
      re += d * v.x; im += d * v.y;
    }
    X21[(size_t)M * LMAX * 32 + l * 32 + wh * 16 + b] = make_float2(re, im);
  }
}

// ---------------------------------------------------------------------------
// K3 core1 (900 = j*15+mq): M-quad Mbase = mq*4.
//  stage sg (mirror+sign for M>=30) -> sC -> T1h[j][M][u]
// ---------------------------------------------------------------------------
__global__ __launch_bounds__(256)
void k_core1(const float2* __restrict__ X2, const float* __restrict__ sgd,
             const float2* __restrict__ scwF, __half2* __restrict__ Th) {
  __shared__ float  sg[4][LMAX][NTP];     //  5760
  __shared__ float2 scw[NT * NPAIR];      //  1760
  __shared__ float2 sC[4][LMAX][NPAIR];   // 19200
  int t = threadIdx.x;
  int j = blockIdx.x / 15, mq = blockIdx.x - 15 * j;
  int Mbase = mq * 4;
  for (int q = t; q < NT * NPAIR; q += 256) scw[q] = scwF[q];
  for (int q = t; q < 4 * LMAX * NTP; q += 256) {
    int Mi = q / 360, r = q - Mi * 360;
    int l = r / NTP, nn = r - l * NTP;
    int M = Mbase + Mi;
    float v = 0.f;
    if (M < MWC && nn < NT) {
      if (M < 30) {
        v = sgd[(size_t)(j * 30 + M) * 360 + r];
      } else {
        v = sgd[(size_t)(j * 30 + 58 - M) * 360 + l * NTP + (10 - nn)];
        if (!(M & 1)) v = -v;   // (-1)^(M-29)
      }
    }
    ((float*)sg)[q] = v;
  }
  __syncthreads();
  for (int q = t; q < 4 * LMAX * NPAIR; q += 256) {
    int Mi = q / 600, r = q - Mi * 600;
    int l = r / NPAIR, pair = r - l * NPAIR;
    float cre = 0.f, cim = 0.f;
#pragma unroll
    for (int nn = 0; nn < NT; ++nn) {
      float g = sg[Mi][l][nn];
      float2 c = scw[nn * NPAIR + pair];
      cre += g * c.x; cim += g * c.y;
    }
    ((float2*)sC)[q] = make_float2(cre, cim);
  }
  __syncthreads();
  for (int q = t; q < 4 * 160; q += 256) {
    int Mi = q / 160, u = q - Mi * 160;
    int M = Mbase + Mi;
    if (M >= MWC) continue;
    int bb = u / 10, o = u - 10 * bb;
    float tre = 0.f, tim = 0.f;
#pragma unroll 6
    for (int l = 0; l < LMAX; ++l) {
#pragma unroll
      for (int i = 0; i < 2; ++i) {
        float2 xv = X2[((size_t)M * LMAX + l) * 32 + i * 16 + bb];
        float2 cv = sC[Mi][l][i * 10 + o];
        tre += xv.x * cv.x - xv.y * cv.y;
        tim += xv.x * cv.y + xv.y * cv.x;
      }
    }
    Th[((size_t)j * MWC + M) * 160 + u] = __floats2half2_rn(tre, tim);
  }
}

// ---------------------------------------------------------------------------
// K4 ana2 (944 = M*16 + c): stage-2 analysis, 10-u chunks, fused bridge.
//   xf2[j][u] = T1[j][M][u] + conj(T1[j][58-M][u])  (pi folded into scwF2)
//   X22[M][l][w*16+c] = sum_j D0T[M,l,j] * xf2[j][c*10+w]   ([i][b] layout)
// ---------------------------------------------------------------------------
__global__ __launch_bounds__(256)
void k_ana2(const __half2* __restrict__ T1, const float* __restrict__ D0T,
            float2* __restrict__ X22) {
  __shared__ float2 sxf[NBG][10];   // 4800
  __shared__ float  sD[LMAX][NBG];  // 7200
  int M = blockIdx.x >> 4, c = blockIdx.x & 15;
  int u0 = c * 10, t = threadIdx.x;
  for (int q = t; q < NBG * 10; q += 256) {
    int jj = q / 10, w = q - jj * 10;
    float2 v1 = __half22float2(T1[((size_t)jj * MWC + M) * 160 + u0 + w]);
    float2 v2 = __half22float2(T1[((size_t)jj * MWC + (58 - M)) * 160 + u0 + w]);
    sxf[jj][w] = make_float2(v1.x + v2.x, v1.y - v2.y);
  }
  for (int q = t; q < LMAX * NBG; q += 256) ((float*)sD)[q] = D0T[(size_t)M * LMAX * NBG + q];
  __syncthreads();
  for (int q = t; q < LMAX * 10; q += 256) {
    int l = q / 10, w = q - l * 10;
    float re = 0.f, im = 0.f;
#pragma unroll 6
    for (int jj = 0; jj < NBG; ++jj) {
      float d = sD[l][jj];
      float2 v = sxf[jj][w];
      re += d * v.x; im += d * v.y;
    }
    X22[((size_t)M * LMAX + l) * 160 + w * 16 + c] = make_float2(re, im);
  }
}

// ---------------------------------------------------------------------------
// K5 core2 (900 = j*15+mq): M-quad, 2-way l-split + LDS reduce -> T2[j][M][u]
// ---------------------------------------------------------------------------
__global__ __launch_bounds__(256)
void k_core2(const float2* __restrict__ X2, const float* __restrict__ sgd,
             const float2* __restrict__ scwF, float2* __restrict__ Tf) {
  __shared__ float  sg[4][LMAX][NTP];     //  5760
  __shared__ float2 scw[NT * NPAIR];      //  1760
  __shared__ float2 sC[4][LMAX][NPAIR];   // 19200
  __shared__ float2 sRed[256];            //  2048
  int t = threadIdx.x;
  int j = blockIdx.x / 15, mq = blockIdx.x - 15 * j;
  int Mbase = mq * 4;
  for (int q = t; q < NT * NPAIR; q += 256) scw[q] = scwF[q];
  for (int q = t; q < 4 * LMAX * NTP; q += 256) {
    int Mi = q / 360, r = q - Mi * 360;
    int l = r / NTP, nn = r - l * NTP;
    int M = Mbase + Mi;
    float v = 0.f;
    if (M < MWC && nn < NT) {
      if (M < 30) {
        v = sgd[(size_t)(j * 30 + M) * 360 + r];
      } else {
        v = sgd[(size_t)(j * 30 + 58 - M) * 360 + l * NTP + (10 - nn)];
        if (!(M & 1)) v = -v;
      }
    }
    ((float*)sg)[q] = v;
  }
  __syncthreads();
  for (int q = t; q < 4 * LMAX * NPAIR; q += 256) {
    int Mi = q / 600, r = q - Mi * 600;
    int l = r / NPAIR, pair = r - l * NPAIR;
    float cre = 0.f, cim = 0.f;
#pragma unroll
    for (int nn = 0; nn < NT; ++nn) {
      float g = sg[Mi][l][nn];
      float2 c = scw[nn * NPAIR + pair];
      cre += g * c.x; cim += g * c.y;
    }
    ((float2*)sC)[q] = make_float2(cre, cim);
  }
  __syncthreads();
  int sub = t >> 7, idx = t & 127;
  int Mi = idx >> 5, u = idx & 31;
  int M = Mbase + Mi;
  int bb = u >> 1, o = u & 1;
  float tre = 0.f, tim = 0.f;
  if (M < MWC) {
    for (int l = sub; l < LMAX; l += 2) {
#pragma unroll
      for (int i = 0; i < 10; ++i) {
        float2 xv = X2[((size_t)M * LMAX + l) * 160 + i * 16 + bb];
        float2 cv = sC[Mi][l][i * 2 + o];
        tre += xv.x * cv.x - xv.y * cv.y;
        tim += xv.x * cv.y + xv.y * cv.x;
      }
    }
  }
  sRed[t] = make_float2(tre, tim);
  __syncthreads();
  if (t < 128 && M < MWC) {
    float2 a0 = sRed[t], a1 = sRed[t + 128];
    Tf[((size_t)j * MWC + M) * 32 + u] = make_float2(a0.x + a1.x, a0.y + a1.y);
  }
}

// ---------------------------------------------------------------------------
// K6 synth (240 = j*4+uq): out[u][j][a] = Re sum_M T2[j][M][u] e^{+2pi i(M-29)a/60}
// ---------------------------------------------------------------------------
__global__ __launch_bounds__(256)
void k_synth2(const float2* __restrict__ T2, float* __restrict__ out) {
  __shared__ float2 sT[MWC][8];     // 3776
  __shared__ float twc[NBG], tws[NBG];
  int j = blockIdx.x >> 2, uq = blockIdx.x & 3;
  int u0 = uq * 8, t = threadIdx.x;
  for (int q = t; q < MWC * 8; q += 256) {
    int M = q >> 3, uu = q & 7;
    sT[M][uu] = T2[((size_t)j * MWC + M) * 32 + u0 + uu];
  }
  if (t < NBG) {
    float s, c; sincosf(2.f * PI_F * t / 60.f, &s, &c);
    twc[t] = c; tws[t] = s;
  }
  __syncthreads();
  for (int q = t; q < 8 * NBG; q += 256) {
    int uu = q / NBG, a = q - uu * NBG;
    int k = (31 * a) % NBG;          // (-29*a) mod 60
    float acc = 0.f;
#pragma unroll 4
    for (int M = 0; M < MWC; ++M) {
      float2 v = sT[M][uu];
      acc += v.x * twc[k] - v.y * tws[k];
      k += a; if (k >= NBG) k -= NBG;
    }
    out[((size_t)(u0 + uu) * NBG + j) * NBG + a] = acc;
  }
}

// ---------------------------------------------------------------------------
extern "C" void kernel_launch(void* const* d_in, const int* in_sizes, int n_in,
                              void* d_out, int out_size, void* d_ws, size_t ws_size,
                              hipStream_t stream) {
  const float* x1 = (const float*)d_in[0];
  const float* wc = (const float*)d_in[1];
  const float* wd = (const float*)d_in[2];
  float* out = (float*)d_out;
  char* ws = (char*)d_ws;

  // workspace layout (peak 8.01 MB, proven r7-r10)
  float2*  scwF1 = (float2*) (ws + 0);        // 220 c64
  float2*  scwF2 = (float2*) (ws + 2048);
  float*   D0T   = (float*)  (ws + 4096);     // 59*30*60 f32
  float*   sgd   = (float*)  (ws + 430080);   // 60*30*360 f32
  char*    R1    = ws + 3022592;              // xfT (906240) then X22 (2265600)
  char*    R2    = ws + 5288192;              // T1 half2 (2265600); T2 aliases (906240)
  float2*  X21   = (float2*) (ws + 7553792);  // 453120
  float2*  xfT   = (float2*) R1;
  float2*  X22   = (float2*) R1;
  __half2* T1    = (__half2*)R2;
  float2*  T2    = (float2*) R2;

  k1_prep <<<780, 256, 0, stream>>>(x1, wc, wd, scwF1, scwF2, D0T, sgd, xfT);
  k_ana1  <<<472, 128, 0, stream>>>(xfT, D0T, X21);
  k_core1 <<<900, 256, 0, stream>>>(X21, sgd, scwF1, T1);
  k_ana2  <<<944, 256, 0, stream>>>(T1, D0T, X22);
  k_core2 <<<900, 256, 0, stream>>>(X22, sgd, scwF2, T2);
  k_synth2<<<240, 256, 0, stream>>>(T2, out);
}

// Round 12
// 96.890 us; speedup vs baseline: 1.0113x; 1.0113x over previous
//
#include <hip/hip_runtime.h>
#include <hip/hip_fp16.h>

#define NBG   60
#define LMAX  30
#define MWC   59
#define CTR   29
#define NPAIR 20
#define NT    11          // |n| <= 5 truncation (validated r4-r11)
#define NTP   12
#define NOFF  5
#define PI_F  3.14159265358979323846f

// ---------------------------------------------------------------------------
// f32 Wigner small-d column scale*d^l_{mp,mn}(beta), Jacobi recurrence.
// Convention == expm(-(beta/2)(J+ - J-)), verified on-hardware r1-r11.
// ---------------------------------------------------------------------------
__device__ void wigner_colf(float beta, int mp, int mn, float scale,
                            float* out, int stride) {
  int a = mp - mn; if (a < 0) a = -a;
  int b = mp + mn; if (b < 0) b = -b;
  int lmin = (a + b) >> 1;
  for (int l = 0; l < LMAX; ++l) out[l * stride] = 0.0f;
  if (lmin >= LMAX) return;
  float sh, ch; sincosf(0.5f * beta, &sh, &ch);
  float x = ch * ch - sh * sh;
  float base = scale;
  for (int q = 0; q < a; ++q) base *= sh;
  for (int q = 0; q < b; ++q) base *= ch;
  if (mp >= mn && ((mp - mn) & 1)) base = -base;
  float K2 = 1.f;
  for (int q = 1; q <= a; ++q) K2 *= (float)(b + q) / (float)q;
  float Pm2 = 0.f, Pm1 = 1.f;
  out[lmin * stride] = base * sqrtf(K2);
  for (int s = 1; lmin + s < LMAX; ++s) {
    float Ps;
    if (s == 1) {
      Ps = (a + 1) + (a + b + 2) * 0.5f * (x - 1.f);
    } else {
      float t0 = 2.f * s + a + b;
      float c1 = 2.f * s * (s + a + b) * (t0 - 2.f);
      float c2 = (t0 - 1.f) * (t0 * (t0 - 2.f) * x + (float)(a * a - b * b));
      float c3 = 2.f * (s + a - 1.f) * (s + b - 1.f) * t0;
      Ps = (c2 * Pm1 - c3 * Pm2) / c1;
    }
    K2 *= ((float)s * (s + a + b)) / (((float)s + a) * ((float)s + b));
    out[(lmin + s) * stride] = base * sqrtf(K2) * Ps;
    Pm2 = Pm1; Pm1 = Ps;
  }
}

__device__ __forceinline__ float quad_w(int j) {
  float s = 0.f;
  for (int k = 0; k < 30; ++k) {
    int r = ((2 * j + 1) * (2 * k + 1)) % 240;
    s += sinf(2.f * PI_F * r / 240.f) / (float)(2 * k + 1);
  }
  return (2.f / 30.f) * sinf(PI_F * (2 * j + 1) / 120.f) * s;
}

// ---------------------------------------------------------------------------
// K1 (772 blocks x 256): ALL input-only work, incl. self-sufficient fused
// DFT+analysis (stage 1). No cross-block dependencies inside this kernel.
//  u 0        : scwF1/scwF2[nn][pair]  (scwF2 x pi for the synth/fft bridge)
//  u 1..59    : M = u-1: D0T[M][l][j] = wq[j]*d^l_{M-29,0}(beta_j)  (for ana2)
//  u 60..299  : sgd[j][M][l][nn] = d^l_{M-29,nn-5}(beta_j)*(2l+1)*dk[l][nn]
//  u 300..771 : fused dft+ana1 (bi = u-300: M=bi>>3, lq=(bi>>1)&3, wh=bi&1):
//               in-block single-M DFT of x1 rows r=2b+wh + in-block Wigner
//               slice -> X21[M][l][wh*16+b] = sum_j wq_j d^l_{M',0} xf[j][b]
// ---------------------------------------------------------------------------
__global__ __launch_bounds__(256)
void k1_prep(const float* __restrict__ x1,
             const float* __restrict__ wc, const float* __restrict__ wd,
             float2* __restrict__ scwF1, float2* __restrict__ scwF2,
             float* __restrict__ D0T, float* __restrict__ sgd,
             float2* __restrict__ X21) {
  __shared__ __align__(16) char smem[15360];
  int u = blockIdx.x, t = threadIdx.x;
  if (u == 0) {
    float*  swq  = (float*)smem;
    float2* swqn = (float2*)(smem + 256);
    if (t < NBG) swq[t] = quad_w(t);
    __syncthreads();
    if (t < NT) {
      int n = t - NOFF;
      float re = 0.f, im = 0.f;
      for (int g = 0; g < NBG; ++g) {
        int k = ((n * g) % NBG + NBG) % NBG;
        float sn, cs; sincosf(2.f * PI_F * k / 60.f, &sn, &cs);
        re += swq[g] * cs; im += swq[g] * sn;
      }
      swqn[t] = make_float2(re, im);
    }
    __syncthreads();
    if (t < NT * NPAIR) {
      int nn = t / NPAIR, pair = t - nn * NPAIR, n = nn - NOFF;
      float re1 = 0, im1 = 0, re2 = 0, im2 = 0;
      for (int p = 0; p < 6; ++p) {
        int k = ((n * p) % 6 + 6) % 6;
        float sn, cs; sincosf(2.f * PI_F * k / 6.f, &sn, &cs);
        float a1 = wc[pair * 6 + p], a2 = wd[pair * 6 + p];
        re1 += a1 * cs; im1 += a1 * sn;
        re2 += a2 * cs; im2 += a2 * sn;
      }
      float2 w = swqn[nn];
      scwF1[t] = make_float2(w.x * re1 - w.y * im1, w.x * im1 + w.y * re1);
      scwF2[t] = make_float2(PI_F * (w.x * re2 - w.y * im2),
                             PI_F * (w.x * im2 + w.y * re2));
    }
  } else if (u < 60) {
    int M = u - 1;
    if (t < NBG) {
      float wqj = quad_w(t);
      wigner_colf(PI_F * (2 * t + 1) / 120.f, M - CTR, 0, wqj,
                  D0T + (size_t)M * LMAX * NBG + t, NBG);
    }
  } else if (u < 300) {
    float* buf  = (float*)smem;            // [8][30][12] 11520
    float* dkwL = (float*)(smem + 11520);  // [30][12] 1440
    int s = u - 60, j = s >> 2, c = s & 3;
    int M0 = c * 8, nM = (c < 3) ? 8 : 6;
    if (t < nM * NT) {
      int Mi = t / NT, nn = t - Mi * NT;
      wigner_colf(PI_F * (2 * j + 1) / 120.f, M0 + Mi - CTR, nn - NOFF, 1.f,
                  &buf[Mi * 360 + nn], NTP);
    } else if (t >= 128 && t < 128 + NT) {
      int nn = t - 128;
      wigner_colf(PI_F / 160.f, nn - NOFF, 0, 1.f, dkwL + nn, NTP);
      for (int l = 0; l < LMAX; ++l) dkwL[l * NTP + nn] *= (float)(2 * l + 1);
    }
    __syncthreads();
    size_t base = (size_t)(j * 30 + M0) * 360;
    for (int q = t; q < nM * 360; q += 256) {
      int r = q % 360, nn = r % NTP;
      sgd[base + q] = (nn < NT) ? buf[q] * dkwL[r] : 0.f;
    }
  } else {
    // ---- fused single-M DFT + S2 analysis (self-sufficient) ----
    float*  twc = (float*)smem;            // 240
    float*  tws = (float*)(smem + 240);    // 240
    float2* sxf = (float2*)(smem + 480);   // [60][16] 7680 -> 8160
    float*  sDf = (float*)(smem + 8160);   // [30][60] 7200 -> 15360
    int bi = u - 300;
    int M = bi >> 3, lq = (bi >> 1) & 3, wh = bi & 1;
    int mm = M - CTR;
    if (t < NBG) {
      float sn, cs; sincosf(-2.f * PI_F * t / 60.f, &sn, &cs);
      twc[t] = cs; tws[t] = sn;
    }
    if (t >= 64 && t < 64 + NBG) {      // wave 1: Wigner slice for this M
      int j = t - 64;
      float wqj = quad_w(j);
      wigner_colf(PI_F * (2 * j + 1) / 120.f, mm, 0, wqj, sDf + j, NBG);
    }
    __syncthreads();
    for (int q = t; q < NBG * 16; q += 256) {     // DFT: xf[j][b], row r=2b+wh
      int j = q >> 4, b = q & 15;
      const float* xp = x1 + ((size_t)(2 * b + wh) * NBG + j) * NBG;
      float re = 0.f, im = 0.f; int k = 0;
#pragma unroll
      for (int a = 0; a < NBG; ++a) {
        re += xp[a] * twc[k]; im += xp[a] * tws[k];
        k += mm; if (k >= NBG) k -= NBG; if (k < 0) k += NBG;
      }
      const float sc = 2.f * PI_F / 60.f;
      sxf[q] = make_float2(re * sc, im * sc);
    }
    __syncthreads();
    if (t < 128) {
      int ll = t >> 4, b = t & 15;
      int l = lq * 8 + ll;
      if (l < LMAX) {
        float re = 0.f, im = 0.f;
#pragma unroll 6
        for (int jj = 0; jj < NBG; ++jj) {
          float d = sDf[l * NBG + jj];
          float2 v = sxf[jj * 16 + b];
          re += d * v.x; im += d * v.y;
        }
        X21[(size_t)M * LMAX * 32 + l * 32 + wh * 16 + b] = make_float2(re, im);
      }
    }
  }
}

// ---------------------------------------------------------------------------
// K3 core1 (1800 = j*30+mg): M = 2mg, 2mg+1.  (r10 proven body)
// ---------------------------------------------------------------------------
__global__ __launch_bounds__(256)
void k_core1(const float2* __restrict__ X2, const float* __restrict__ sgd,
             const float2* __restrict__ scwF, __half2* __restrict__ Th) {
  __shared__ float  sg[2][LMAX][NTP];     //  2880
  __shared__ float2 scw[NT * NPAIR];      //  1760
  __shared__ float2 sC[2][LMAX][NPAIR];   //  9600
  int t = threadIdx.x;
  int j = blockIdx.x / 30, mg = blockIdx.x - 30 * j;
  int Mbase = mg * 2;
  for (int q = t; q < NT * NPAIR; q += 256) scw[q] = scwF[q];
  for (int q = t; q < 2 * LMAX * NTP; q += 256) {
    int Mi = q / (LMAX * NTP), r = q - Mi * LMAX * NTP;
    int l = r / NTP, nn = r - l * NTP;
    int M = Mbase + Mi;
    float v = 0.f;
    if (M < MWC && nn < NT) {
      if (M < 30) {
        v = sgd[(size_t)(j * 30 + M) * 360 + r];
      } else {
        v = sgd[(size_t)(j * 30 + 58 - M) * 360 + l * NTP + (10 - nn)];
        if (!(M & 1)) v = -v;   // (-1)^(M-29)
      }
    }
    ((float*)sg)[q] = v;
  }
  __syncthreads();
  for (int q = t; q < 2 * LMAX * NPAIR; q += 256) {
    int Mi = q / (LMAX * NPAIR), r = q - Mi * LMAX * NPAIR;
    int l = r / NPAIR, pair = r - l * NPAIR;
    float cre = 0.f, cim = 0.f;
#pragma unroll
    for (int nn = 0; nn < NT; ++nn) {
      float g = sg[Mi][l][nn];
      float2 c = scw[nn * NPAIR + pair];
      cre += g * c.x; cim += g * c.y;
    }
    ((float2*)sC)[q] = make_float2(cre, cim);
  }
  __syncthreads();
  for (int q = t; q < 2 * 160; q += 256) {
    int Mi = q / 160, u = q - Mi * 160;
    int M = Mbase + Mi;
    if (M >= MWC) continue;
    int bb = u / 10, o = u - 10 * bb;
    float tre = 0.f, tim = 0.f;
#pragma unroll 6
    for (int l = 0; l < LMAX; ++l) {
#pragma unroll
      for (int i = 0; i < 2; ++i) {
        float2 xv = X2[((size_t)M * LMAX + l) * 32 + i * 16 + bb];
        float2 cv = sC[Mi][l][i * 10 + o];
        tre += xv.x * cv.x - xv.y * cv.y;
        tim += xv.x * cv.y + xv.y * cv.x;
      }
    }
    Th[((size_t)j * MWC + M) * 160 + u] = __floats2half2_rn(tre, tim);
  }
}

// ---------------------------------------------------------------------------
// K4 ana2 (944 = M*16 + c): stage-2 analysis, 10-u chunks, fused bridge.
//   xf2[j][u] = T1[j][M][u] + conj(T1[j][58-M][u])  (pi folded into scwF2)
//   X22[M][l][w*16+c] = sum_j D0T[M,l,j] * xf2[j][c*10+w]   ([i][b] layout)
// ---------------------------------------------------------------------------
__global__ __launch_bounds__(256)
void k_ana2(const __half2* __restrict__ T1, const float* __restrict__ D0T,
            float2* __restrict__ X22) {
  __shared__ float2 sxf[NBG][10];   // 4800
  __shared__ float  sD[LMAX][NBG];  // 7200
  int M = blockIdx.x >> 4, c = blockIdx.x & 15;
  int u0 = c * 10, t = threadIdx.x;
  for (int q = t; q < NBG * 10; q += 256) {
    int jj = q / 10, w = q - jj * 10;
    float2 v1 = __half22float2(T1[((size_t)jj * MWC + M) * 160 + u0 + w]);
    float2 v2 = __half22float2(T1[((size_t)jj * MWC + (58 - M)) * 160 + u0 + w]);
    sxf[jj][w] = make_float2(v1.x + v2.x, v1.y - v2.y);
  }
  for (int q = t; q < LMAX * NBG; q += 256) ((float*)sD)[q] = D0T[(size_t)M * LMAX * NBG + q];
  __syncthreads();
  for (int q = t; q < LMAX * 10; q += 256) {
    int l = q / 10, w = q - l * 10;
    float re = 0.f, im = 0.f;
#pragma unroll 6
    for (int jj = 0; jj < NBG; ++jj) {
      float d = sD[l][jj];
      float2 v = sxf[jj][w];
      re += d * v.x; im += d * v.y;
    }
    X22[((size_t)M * LMAX + l) * 160 + w * 16 + c] = make_float2(re, im);
  }
}

// ---------------------------------------------------------------------------
// K5 core2 (1800 = j*30+mg): 4-way l-split + LDS reduce -> T2[j][M][u]
// ---------------------------------------------------------------------------
__global__ __launch_bounds__(256)
void k_core2(const float2* __restrict__ X2, const float* __restrict__ sgd,
             const float2* __restrict__ scwF, float2* __restrict__ Tf) {
  __shared__ float  sg[2][LMAX][NTP];
  __shared__ float2 scw[NT * NPAIR];
  __shared__ float2 sC[2][LMAX][NPAIR];
  __shared__ float2 sRed[256];
  int t = threadIdx.x;
  int j = blockIdx.x / 30, mg = blockIdx.x - 30 * j;
  int Mbase = mg * 2;
  for (int q = t; q < NT * NPAIR; q += 256) scw[q] = scwF[q];
  for (int q = t; q < 2 * LMAX * NTP; q += 256) {
    int Mi = q / (LMAX * NTP), r = q - Mi * LMAX * NTP;
    int l = r / NTP, nn = r - l * NTP;
    int M = Mbase + Mi;
    float v = 0.f;
    if (M < MWC && nn < NT) {
      if (M < 30) {
        v = sgd[(size_t)(j * 30 + M) * 360 + r];
      } else {
        v = sgd[(size_t)(j * 30 + 58 - M) * 360 + l * NTP + (10 - nn)];
        if (!(M & 1)) v = -v;
      }
    }
    ((float*)sg)[q] = v;
  }
  __syncthreads();
  for (int q = t; q < 2 * LMAX * NPAIR; q += 256) {
    int Mi = q / (LMAX * NPAIR), r = q - Mi * LMAX * NPAIR;
    int l = r / NPAIR, pair = r - l * NPAIR;
    float cre = 0.f, cim = 0.f;
#pragma unroll
    for (int nn = 0; nn < NT; ++nn) {
      float g = sg[Mi][l][nn];
      float2 c = scw[nn * NPAIR + pair];
      cre += g * c.x; cim += g * c.y;
    }
    ((float2*)sC)[q] = make_float2(cre, cim);
  }
  __syncthreads();
  int sub = t >> 6, idx = t & 63;
  int Mi = idx >> 5, u = idx & 31;
  int M = Mbase + Mi;
  int bb = u >> 1, o = u & 1;
  float tre = 0.f, tim = 0.f;
  if (M < MWC) {
    for (int l = sub; l < LMAX; l += 4) {
#pragma unroll
      for (int i = 0; i < 10; ++i) {
        float2 xv = X2[((size_t)M * LMAX + l) * 160 + i * 16 + bb];
        float2 cv = sC[Mi][l][i * 2 + o];
        tre += xv.x * cv.x - xv.y * cv.y;
        tim += xv.x * cv.y + xv.y * cv.x;
      }
    }
  }
  sRed[t] = make_float2(tre, tim);
  __syncthreads();
  if (t < 64 && M < MWC) {
    float2 a0 = sRed[t], a1 = sRed[t + 64], a2 = sRed[t + 128], a3 = sRed[t + 192];
    Tf[((size_t)j * MWC + M) * 32 + u] =
        make_float2(a0.x + a1.x + a2.x + a3.x, a0.y + a1.y + a2.y + a3.y);
  }
}

// ---------------------------------------------------------------------------
// K6 synth (240 = j*4+uq): out[u][j][a] = Re sum_M T2[j][M][u] e^{+2pi i(M-29)a/60}
// ---------------------------------------------------------------------------
__global__ __launch_bounds__(256)
void k_synth2(const float2* __restrict__ T2, float* __restrict__ out) {
  __shared__ float2 sT[MWC][8];     // 3776
  __shared__ float twc[NBG], tws[NBG];
  int j = blockIdx.x >> 2, uq = blockIdx.x & 3;
  int u0 = uq * 8, t = threadIdx.x;
  for (int q = t; q < MWC * 8; q += 256) {
    int M = q >> 3, uu = q & 7;
    sT[M][uu] = T2[((size_t)j * MWC + M) * 32 + u0 + uu];
  }
  if (t < NBG) {
    float s, c; sincosf(2.f * PI_F * t / 60.f, &s, &c);
    twc[t] = c; tws[t] = s;
  }
  __syncthreads();
  for (int q = t; q < 8 * NBG; q += 256) {
    int uu = q / NBG, a = q - uu * NBG;
    int k = (31 * a) % NBG;          // (-29*a) mod 60
    float acc = 0.f;
#pragma unroll 4
    for (int M = 0; M < MWC; ++M) {
      float2 v = sT[M][uu];
      acc += v.x * twc[k] - v.y * tws[k];
      k += a; if (k >= NBG) k -= NBG;
    }
    out[((size_t)(u0 + uu) * NBG + j) * NBG + a] = acc;
  }
}

// ---------------------------------------------------------------------------
extern "C" void kernel_launch(void* const* d_in, const int* in_sizes, int n_in,
                              void* d_out, int out_size, void* d_ws, size_t ws_size,
                              hipStream_t stream) {
  const float* x1 = (const float*)d_in[0];
  const float* wc = (const float*)d_in[1];
  const float* wd = (const float*)d_in[2];
  float* out = (float*)d_out;
  char* ws = (char*)d_ws;

  // workspace layout (peak 8.01 MB, proven r7-r11); xfT eliminated
  float2*  scwF1 = (float2*) (ws + 0);        // 220 c64
  float2*  scwF2 = (float2*) (ws + 2048);
  float*   D0T   = (float*)  (ws + 4096);     // 59*30*60 f32
  float*   sgd   = (float*)  (ws + 430080);   // 60*30*360 f32
  char*    R1    = ws + 3022592;              // X22 (2265600)
  char*    R2    = ws + 5288192;              // T1 half2 (2265600); T2 aliases (906240)
  float2*  X21   = (float2*) (ws + 7553792);  // 453120
  float2*  X22   = (float2*) R1;
  __half2* T1    = (__half2*)R2;
  float2*  T2    = (float2*) R2;

  k1_prep <<<772,  256, 0, stream>>>(x1, wc, wd, scwF1, scwF2, D0T, sgd, X21);
  k_core1 <<<1800, 256, 0, stream>>>(X21, sgd, scwF1, T1);
  k_ana2  <<<944,  256, 0, stream>>>(T1, D0T, X22);
  k_core2 <<<1800, 256, 0, stream>>>(X22, sgd, scwF2, T2);
  k_synth2<<<240,  256, 0, stream>>>(T2, out);
}

// Round 13
// 91.360 us; speedup vs baseline: 1.0725x; 1.0605x over previous
//
#include <hip/hip_runtime.h>
#include <hip/hip_fp16.h>

#define NBG   60
#define LMAX  30
#define MWC   59
#define CTR   29
#define NPAIR 20
#define NT    11          // |n| <= 5 truncation (validated r4-r12)
#define NTP   12
#define NOFF  5
#define PI_F  3.14159265358979323846f

// ---------------------------------------------------------------------------
// f32 Wigner small-d column scale*d^l_{mp,mn}(beta), Jacobi recurrence.
// Convention == expm(-(beta/2)(J+ - J-)), verified on-hardware r1-r12.
// ---------------------------------------------------------------------------
__device__ void wigner_colf(float beta, int mp, int mn, float scale,
                            float* out, int stride) {
  int a = mp - mn; if (a < 0) a = -a;
  int b = mp + mn; if (b < 0) b = -b;
  int lmin = (a + b) >> 1;
  for (int l = 0; l < LMAX; ++l) out[l * stride] = 0.0f;
  if (lmin >= LMAX) return;
  float sh, ch; sincosf(0.5f * beta, &sh, &ch);
  float x = ch * ch - sh * sh;
  float base = scale;
  for (int q = 0; q < a; ++q) base *= sh;
  for (int q = 0; q < b; ++q) base *= ch;
  if (mp >= mn && ((mp - mn) & 1)) base = -base;
  float K2 = 1.f;
  for (int q = 1; q <= a; ++q) K2 *= (float)(b + q) / (float)q;
  float Pm2 = 0.f, Pm1 = 1.f;
  out[lmin * stride] = base * sqrtf(K2);
  for (int s = 1; lmin + s < LMAX; ++s) {
    float Ps;
    if (s == 1) {
      Ps = (a + 1) + (a + b + 2) * 0.5f * (x - 1.f);
    } else {
      float t0 = 2.f * s + a + b;
      float c1 = 2.f * s * (s + a + b) * (t0 - 2.f);
      float c2 = (t0 - 1.f) * (t0 * (t0 - 2.f) * x + (float)(a * a - b * b));
      float c3 = 2.f * (s + a - 1.f) * (s + b - 1.f) * t0;
      Ps = (c2 * Pm1 - c3 * Pm2) / c1;
    }
    K2 *= ((float)s * (s + a + b)) / (((float)s + a) * ((float)s + b));
    out[(lmin + s) * stride] = base * sqrtf(K2) * Ps;
    Pm2 = Pm1; Pm1 = Ps;
  }
}

__device__ __forceinline__ float quad_w(int j) {
  float s = 0.f;
  for (int k = 0; k < 30; ++k) {
    int r = ((2 * j + 1) * (2 * k + 1)) % 240;
    s += sinf(2.f * PI_F * r / 240.f) / (float)(2 * k + 1);
  }
  return (2.f / 30.f) * sinf(PI_F * (2 * j + 1) / 120.f) * s;
}

// ---------------------------------------------------------------------------
// K1 (540 blocks x 256): all input-only work.
//  u 0        : scwF1/scwF2[nn][pair]  (scwF2 x pi for the synth/fft bridge)
//  u 1..59    : M = u-1: D0T[M][l][j] = wq[j]*d^l_{M-29,0}(beta_j)
//  u 60..299  : sgd[j][M][l][nn] = d^l_{M-29,nn-5}(beta_j)*(2l+1)*dk[l][nn]
//  u 300..539 : alpha-DFT of x1 -> xfT[M][j][rb]
// ---------------------------------------------------------------------------
__global__ __launch_bounds__(256)
void k1_prep(const float* __restrict__ x1,
             const float* __restrict__ wc, const float* __restrict__ wd,
             float2* __restrict__ scwF1, float2* __restrict__ scwF2,
             float* __restrict__ D0T, float* __restrict__ sgd,
             float2* __restrict__ xfT) {
  __shared__ __align__(16) char smem[13056];
  int u = blockIdx.x, t = threadIdx.x;
  if (u == 0) {
    float*  swq  = (float*)smem;
    float2* swqn = (float2*)(smem + 256);
    if (t < NBG) swq[t] = quad_w(t);
    __syncthreads();
    if (t < NT) {
      int n = t - NOFF;
      float re = 0.f, im = 0.f;
      for (int g = 0; g < NBG; ++g) {
        int k = ((n * g) % NBG + NBG) % NBG;
        float sn, cs; sincosf(2.f * PI_F * k / 60.f, &sn, &cs);
        re += swq[g] * cs; im += swq[g] * sn;
      }
      swqn[t] = make_float2(re, im);
    }
    __syncthreads();
    if (t < NT * NPAIR) {
      int nn = t / NPAIR, pair = t - nn * NPAIR, n = nn - NOFF;
      float re1 = 0, im1 = 0, re2 = 0, im2 = 0;
      for (int p = 0; p < 6; ++p) {
        int k = ((n * p) % 6 + 6) % 6;
        float sn, cs; sincosf(2.f * PI_F * k / 6.f, &sn, &cs);
        float a1 = wc[pair * 6 + p], a2 = wd[pair * 6 + p];
        re1 += a1 * cs; im1 += a1 * sn;
        re2 += a2 * cs; im2 += a2 * sn;
      }
      float2 w = swqn[nn];
      scwF1[t] = make_float2(w.x * re1 - w.y * im1, w.x * im1 + w.y * re1);
      scwF2[t] = make_float2(PI_F * (w.x * re2 - w.y * im2),
                             PI_F * (w.x * im2 + w.y * re2));
    }
  } else if (u < 60) {
    int M = u - 1;
    if (t < NBG) {
      float wqj = quad_w(t);
      wigner_colf(PI_F * (2 * t + 1) / 120.f, M - CTR, 0, wqj,
                  D0T + (size_t)M * LMAX * NBG + t, NBG);
    }
  } else if (u < 300) {
    float* buf  = (float*)smem;            // [8][30][12] 11520
    float* dkwL = (float*)(smem + 11520);  // [30][12] 1440
    int s = u - 60, j = s >> 2, c = s & 3;
    int M0 = c * 8, nM = (c < 3) ? 8 : 6;
    if (t < nM * NT) {
      int Mi = t / NT, nn = t - Mi * NT;
      wigner_colf(PI_F * (2 * j + 1) / 120.f, M0 + Mi - CTR, nn - NOFF, 1.f,
                  &buf[Mi * 360 + nn], NTP);
    } else if (t >= 128 && t < 128 + NT) {
      int nn = t - 128;
      wigner_colf(PI_F / 160.f, nn - NOFF, 0, 1.f, dkwL + nn, NTP);
      for (int l = 0; l < LMAX; ++l) dkwL[l * NTP + nn] *= (float)(2 * l + 1);
    }
    __syncthreads();
    size_t base = (size_t)(j * 30 + M0) * 360;
    for (int q = t; q < nM * 360; q += 256) {
      int r = q % 360, nn = r % NTP;
      sgd[base + q] = (nn < NT) ? buf[q] * dkwL[r] : 0.f;
    }
  } else {
    float*  xr  = (float*)smem;            // [8][60] 1920
    float*  twc = (float*)(smem + 1920);
    float*  tws = (float*)(smem + 2160);
    float2* xo  = (float2*)(smem + 2400);  // [59][9] 4248
    int s = u - 300, j = s >> 2, qh = s & 3;
    for (int q = t; q < 8 * NBG; q += 256) {
      int bl = q / NBG, a = q - bl * NBG;
      xr[bl * NBG + a] = x1[((size_t)(qh * 8 + bl) * NBG + j) * NBG + a];
    }
    if (t < NBG) {
      float sn, cs; sincosf(-2.f * PI_F * t / 60.f, &sn, &cs);
      twc[t] = cs; tws[t] = sn;
    }
    __syncthreads();
    for (int q = t; q < 8 * MWC; q += 256) {
      int bl = q / MWC, M = q - bl * MWC, mm = M - CTR;
      const float* xp = xr + bl * NBG;
      float re = 0.f, im = 0.f; int k = 0;
      for (int a = 0; a < NBG; ++a) {
        re += xp[a] * twc[k]; im += xp[a] * tws[k];
        k += mm; if (k >= NBG) k -= NBG; if (k < 0) k += NBG;
      }
      const float sc = 2.f * PI_F / 60.f;
      xo[M * 9 + bl] = make_float2(re * sc, im * sc);
    }
    __syncthreads();
    for (int q = t; q < MWC * 8; q += 256) {
      int M = q / 8, bl = q - M * 8;
      xfT[((size_t)M * NBG + j) * 32 + qh * 8 + bl] = xo[M * 9 + bl];
    }
  }
}

// ---------------------------------------------------------------------------
// K2 ana1 (472 = M*8 + lq*2 + wh): 8 l's x 16 w's per block (w = wh*16+b).
// X21[M][l][w] = sum_j D0T[M,l,j] * xfT[M,j,2b+wh]
// ---------------------------------------------------------------------------
__global__ __launch_bounds__(256)
void k_ana1(const float2* __restrict__ xfT, const float* __restrict__ D0T,
            float2* __restrict__ X21) {
  __shared__ float2 sxf[NBG][16];   // 7680
  __shared__ float  sD[8][NBG];     // 1920
  int bi = blockIdx.x;
  int M = bi >> 3, lq = (bi >> 1) & 3, wh = bi & 1;
  int t = threadIdx.x;
  for (int q = t; q < NBG * 16; q += 256) {
    int jj = q >> 4, b = q & 15;
    sxf[jj][b] = xfT[((size_t)M * NBG + jj) * 32 + b * 2 + wh];
  }
  for (int q = t; q < 8 * NBG; q += 256) {
    int ll = q / NBG, jj = q - ll * NBG, l = lq * 8 + ll;
    sD[ll][jj] = (l < LMAX) ? D0T[((size_t)M * LMAX + l) * NBG + jj] : 0.f;
  }
  __syncthreads();
  if (t < 128) {
    int ll = t >> 4, b = t & 15;
    int l = lq * 8 + ll;
    if (l < LMAX) {
      float re = 0.f, im = 0.f;
#pragma unroll 6
      for (int jj = 0; jj < NBG; ++jj) {
        float d = sD[ll][jj];
        float2 v = sxf[jj][b];
        re += d * v.x; im += d * v.y;
      }
      X21[(size_t)M * LMAX * 32 + l * 32 + wh * 16 + b] = make_float2(re, im);
    }
  }
}

// ---------------------------------------------------------------------------
// K3 core1 (1800 = j*30+mg): M = 2mg, 2mg+1.  (r7/r10 proven body)
// ---------------------------------------------------------------------------
__global__ __launch_bounds__(256)
void k_core1(const float2* __restrict__ X2, const float* __restrict__ sgd,
             const float2* __restrict__ scwF, __half2* __restrict__ Th) {
  __shared__ float  sg[2][LMAX][NTP];     //  2880
  __shared__ float2 scw[NT * NPAIR];      //  1760
  __shared__ float2 sC[2][LMAX][NPAIR];   //  9600
  int t = threadIdx.x;
  int j = blockIdx.x / 30, mg = blockIdx.x - 30 * j;
  int Mbase = mg * 2;
  for (int q = t; q < NT * NPAIR; q += 256) scw[q] = scwF[q];
  for (int q = t; q < 2 * LMAX * NTP; q += 256) {
    int Mi = q / (LMAX * NTP), r = q - Mi * LMAX * NTP;
    int l = r / NTP, nn = r - l * NTP;
    int M = Mbase + Mi;
    float v = 0.f;
    if (M < MWC && nn < NT) {
      if (M < 30) {
        v = sgd[(size_t)(j * 30 + M) * 360 + r];
      } else {
        v = sgd[(size_t)(j * 30 + 58 - M) * 360 + l * NTP + (10 - nn)];
        if (!(M & 1)) v = -v;   // (-1)^(M-29)
      }
    }
    ((float*)sg)[q] = v;
  }
  __syncthreads();
  for (int q = t; q < 2 * LMAX * NPAIR; q += 256) {
    int Mi = q / (LMAX * NPAIR), r = q - Mi * LMAX * NPAIR;
    int l = r / NPAIR, pair = r - l * NPAIR;
    float cre = 0.f, cim = 0.f;
#pragma unroll
    for (int nn = 0; nn < NT; ++nn) {
      float g = sg[Mi][l][nn];
      float2 c = scw[nn * NPAIR + pair];
      cre += g * c.x; cim += g * c.y;
    }
    ((float2*)sC)[q] = make_float2(cre, cim);
  }
  __syncthreads();
  for (int q = t; q < 2 * 160; q += 256) {
    int Mi = q / 160, u = q - Mi * 160;
    int M = Mbase + Mi;
    if (M >= MWC) continue;
    int bb = u / 10, o = u - 10 * bb;
    float tre = 0.f, tim = 0.f;
#pragma unroll 6
    for (int l = 0; l < LMAX; ++l) {
#pragma unroll
      for (int i = 0; i < 2; ++i) {
        float2 xv = X2[((size_t)M * LMAX + l) * 32 + i * 16 + bb];
        float2 cv = sC[Mi][l][i * 10 + o];
        tre += xv.x * cv.x - xv.y * cv.y;
        tim += xv.x * cv.y + xv.y * cv.x;
      }
    }
    Th[((size_t)j * MWC + M) * 160 + u] = __floats2half2_rn(tre, tim);
  }
}

// ---------------------------------------------------------------------------
// K4 ana2 (944 = M*16 + c): stage-2 analysis, 10-u chunks, fused bridge.
//   xf2[j][u] = T1[j][M][u] + conj(T1[j][58-M][u])  (pi folded into scwF2)
//   X22[M][l][w*16+c] = sum_j D0T[M,l,j] * xf2[j][c*10+w]   ([i][b] layout)
// ---------------------------------------------------------------------------
__global__ __launch_bounds__(256)
void k_ana2(const __half2* __restrict__ T1, const float* __restrict__ D0T,
            float2* __restrict__ X22) {
  __shared__ float2 sxf[NBG][10];   // 4800
  __shared__ float  sD[LMAX][NBG];  // 7200
  int M = blockIdx.x >> 4, c = blockIdx.x & 15;
  int u0 = c * 10, t = threadIdx.x;
  for (int q = t; q < NBG * 10; q += 256) {
    int jj = q / 10, w = q - jj * 10;
    float2 v1 = __half22float2(T1[((size_t)jj * MWC + M) * 160 + u0 + w]);
    float2 v2 = __half22float2(T1[((size_t)jj * MWC + (58 - M)) * 160 + u0 + w]);
    sxf[jj][w] = make_float2(v1.x + v2.x, v1.y - v2.y);
  }
  for (int q = t; q < LMAX * NBG; q += 256) ((float*)sD)[q] = D0T[(size_t)M * LMAX * NBG + q];
  __syncthreads();
  for (int q = t; q < LMAX * 10; q += 256) {
    int l = q / 10, w = q - l * 10;
    float re = 0.f, im = 0.f;
#pragma unroll 6
    for (int jj = 0; jj < NBG; ++jj) {
      float d = sD[l][jj];
      float2 v = sxf[jj][w];
      re += d * v.x; im += d * v.y;
    }
    X22[((size_t)M * LMAX + l) * 160 + w * 16 + c] = make_float2(re, im);
  }
}

// ---------------------------------------------------------------------------
// K5 core2 (1800 = j*30+mg): 4-way l-split + LDS reduce -> T2[j][M][u]
// ---------------------------------------------------------------------------
__global__ __launch_bounds__(256)
void k_core2(const float2* __restrict__ X2, const float* __restrict__ sgd,
             const float2* __restrict__ scwF, float2* __restrict__ Tf) {
  __shared__ float  sg[2][LMAX][NTP];
  __shared__ float2 scw[NT * NPAIR];
  __shared__ float2 sC[2][LMAX][NPAIR];
  __shared__ float2 sRed[256];
  int t = threadIdx.x;
  int j = blockIdx.x / 30, mg = blockIdx.x - 30 * j;
  int Mbase = mg * 2;
  for (int q = t; q < NT * NPAIR; q += 256) scw[q] = scwF[q];
  for (int q = t; q < 2 * LMAX * NTP; q += 256) {
    int Mi = q / (LMAX * NTP), r = q - Mi * LMAX * NTP;
    int l = r / NTP, nn = r - l * NTP;
    int M = Mbase + Mi;
    float v = 0.f;
    if (M < MWC && nn < NT) {
      if (M < 30) {
        v = sgd[(size_t)(j * 30 + M) * 360 + r];
      } else {
        v = sgd[(size_t)(j * 30 + 58 - M) * 360 + l * NTP + (10 - nn)];
        if (!(M & 1)) v = -v;
      }
    }
    ((float*)sg)[q] = v;
  }
  __syncthreads();
  for (int q = t; q < 2 * LMAX * NPAIR; q += 256) {
    int Mi = q / (LMAX * NPAIR), r = q - Mi * LMAX * NPAIR;
    int l = r / NPAIR, pair = r - l * NPAIR;
    float cre = 0.f, cim = 0.f;
#pragma unroll
    for (int nn = 0; nn < NT; ++nn) {
      float g = sg[Mi][l][nn];
      float2 c = scw[nn * NPAIR + pair];
      cre += g * c.x; cim += g * c.y;
    }
    ((float2*)sC)[q] = make_float2(cre, cim);
  }
  __syncthreads();
  int sub = t >> 6, idx = t & 63;
  int Mi = idx >> 5, u = idx & 31;
  int M = Mbase + Mi;
  int bb = u >> 1, o = u & 1;
  float tre = 0.f, tim = 0.f;
  if (M < MWC) {
    for (int l = sub; l < LMAX; l += 4) {
#pragma unroll
      for (int i = 0; i < 10; ++i) {
        float2 xv = X2[((size_t)M * LMAX + l) * 160 + i * 16 + bb];
        float2 cv = sC[Mi][l][i * 2 + o];
        tre += xv.x * cv.x - xv.y * cv.y;
        tim += xv.x * cv.y + xv.y * cv.x;
      }
    }
  }
  sRed[t] = make_float2(tre, tim);
  __syncthreads();
  if (t < 64 && M < MWC) {
    float2 a0 = sRed[t], a1 = sRed[t + 64], a2 = sRed[t + 128], a3 = sRed[t + 192];
    Tf[((size_t)j * MWC + M) * 32 + u] =
        make_float2(a0.x + a1.x + a2.x + a3.x, a0.y + a1.y + a2.y + a3.y);
  }
}

// ---------------------------------------------------------------------------
// K6 synth (240 = j*4+uq): out[u][j][a] = Re sum_M T2[j][M][u] e^{+2pi i(M-29)a/60}
// ---------------------------------------------------------------------------
__global__ __launch_bounds__(256)
void k_synth2(const float2* __restrict__ T2, float* __restrict__ out) {
  __shared__ float2 sT[MWC][8];     // 3776
  __shared__ float twc[NBG], tws[NBG];
  int j = blockIdx.x >> 2, uq = blockIdx.x & 3;
  int u0 = uq * 8, t = threadIdx.x;
  for (int q = t; q < MWC * 8; q += 256) {
    int M = q >> 3, uu = q & 7;
    sT[M][uu] = T2[((size_t)j * MWC + M) * 32 + u0 + uu];
  }
  if (t < NBG) {
    float s, c; sincosf(2.f * PI_F * t / 60.f, &s, &c);
    twc[t] = c; tws[t] = s;
  }
  __syncthreads();
  for (int q = t; q < 8 * NBG; q += 256) {
    int uu = q / NBG, a = q - uu * NBG;
    int k = (31 * a) % NBG;          // (-29*a) mod 60
    float acc = 0.f;
#pragma unroll 4
    for (int M = 0; M < MWC; ++M) {
      float2 v = sT[M][uu];
      acc += v.x * twc[k] - v.y * tws[k];
      k += a; if (k >= NBG) k -= NBG;
    }
    out[((size_t)(u0 + uu) * NBG + j) * NBG + a] = acc;
  }
}

// ---------------------------------------------------------------------------
extern "C" void kernel_launch(void* const* d_in, const int* in_sizes, int n_in,
                              void* d_out, int out_size, void* d_ws, size_t ws_size,
                              hipStream_t stream) {
  const float* x1 = (const float*)d_in[0];
  const float* wc = (const float*)d_in[1];
  const float* wd = (const float*)d_in[2];
  float* out = (float*)d_out;
  char* ws = (char*)d_ws;

  // workspace layout (peak 8.01 MB, proven r7-r12)
  float2*  scwF1 = (float2*) (ws + 0);        // 220 c64
  float2*  scwF2 = (float2*) (ws + 2048);
  float*   D0T   = (float*)  (ws + 4096);     // 59*30*60 f32
  float*   sgd   = (float*)  (ws + 430080);   // 60*30*360 f32
  char*    R1    = ws + 3022592;              // xfT (906240) then X22 (2265600)
  char*    R2    = ws + 5288192;              // T1 half2 (2265600); T2 aliases (906240)
  float2*  X21   = (float2*) (ws + 7553792);  // 453120
  float2*  xfT   = (float2*) R1;
  float2*  X22   = (float2*) R1;
  __half2* T1    = (__half2*)R2;
  float2*  T2    = (float2*) R2;

  k1_prep <<<540,  256, 0, stream>>>(x1, wc, wd, scwF1, scwF2, D0T, sgd, xfT);
  k_ana1  <<<472,  256, 0, stream>>>(xfT, D0T, X21);
  k_core1 <<<1800, 256, 0, stream>>>(X21, sgd, scwF1, T1);
  k_ana2  <<<944,  256, 0, stream>>>(T1, D0T, X22);
  k_core2 <<<1800, 256, 0, stream>>>(X22, sgd, scwF2, T2);
  k_synth2<<<240,  256, 0, stream>>>(T2, out);
}